// Round 7
// baseline (322.634 us; speedup 1.0000x reference)
//
#include <hip/hip_runtime.h>
#include <stdint.h>

// ---------------------------------------------------------------------------
// Attention: out = softmax(Q K^T) V,  N=8, S=2048, E=512, fp32 in/out.
// R13 = R10 with the K-pipeline rotation replaced by a 2x-unrolled ping-pong
// (kfrA/kfrB, no copies). R10's kcur=knxt copy pinned the vmcnt drain at the
// loop back-edge (after PV) and serialized the pipeline; with ping-pong the
// next-tile K loads are issued before b1 and their wait lands naturally at
// the NEXT tile's S-MFMAs -> latency hides under b1+softmax+b2+PV (the same
// mechanism that won R7's V-prefetch). BK stays 32 (R12's BK=64 regressed:
// 4x LDS bank conflicts from the 69-f32 stride + wider register windows).
// Q inline (R8/R10/R12-verified gather, one-time prologue); pre-pass K+V only.
// ---------------------------------------------------------------------------

typedef __attribute__((ext_vector_type(8))) _Float16 half8;   // MFMA A/B frag
typedef __attribute__((ext_vector_type(2))) _Float16 half2;
typedef __attribute__((ext_vector_type(4))) float    floatx4; // MFMA C/D frag

#define NBATCH 8
#define SEQ    2048
#define EDIM   512
static constexpr size_t NE = (size_t)NBATCH * SEQ * EDIM;  // 8388608 elems/tensor

// Barrier WITHOUT vmcnt drain: LDS ordering only; global loads in flight stay
// in flight (their consumers get compiler-inserted vmcnt waits).
__device__ __forceinline__ void block_sync_lds() {
  asm volatile("s_waitcnt lgkmcnt(0)\n\ts_barrier" ::: "memory");
}

__device__ __forceinline__ half8 cvt8(float4 a, float4 b) {
  half8 h;
  h[0] = (_Float16)a.x; h[1] = (_Float16)a.y; h[2] = (_Float16)a.z; h[3] = (_Float16)a.w;
  h[4] = (_Float16)b.x; h[5] = (_Float16)b.y; h[6] = (_Float16)b.z; h[7] = (_Float16)b.w;
  return h;
}

// ---------------------------------------------------------------------------
// Fragment layout contract (A/B-frag 16x16x32): lane l holds
//   [dim16 = l&15][k = (l>>4)*8 + j].
//  K: kf[((n*128 + rt)*16 + est)*512 + lane*8 + j]   (rt = row>>4, est = e>>5)
//  V: vf[((n*64 + kt)*32 + et)*512 + lane*8 + j]     (kt = krow>>5, et = e>>4,
//        dim16 = e-col, k = krow within 32-tile)
// ---------------------------------------------------------------------------

// --- pre-pass: 1024 blocks = 2 segments (K,V) x 8 n x 64 row-tiles. (R10-proven)
__global__ void make_frags(const float* __restrict__ k, const float* __restrict__ v,
                           _Float16* __restrict__ kf, _Float16* __restrict__ vf) {
  __shared__ float lds[32][260];
  const int tid = threadIdx.x;
  const int seg = blockIdx.x >> 9;        // 0=K, 1=V
  const int b   = blockIdx.x & 511;       // 8 n x 64 kt
  const int n = b >> 6, kt = b & 63;
  const float* src = (seg == 0 ? k : v) + ((size_t)n * SEQ + kt * 32) * EDIM;

  if (seg == 0) {
    _Float16* dst = kf + ((size_t)(n * 128 + kt * 2) * 16) * 512;
#pragma unroll
    for (int eh = 0; eh < 2; eh++) {
      if (eh) __syncthreads();
#pragma unroll
      for (int i = 0; i < 8; i++) {       // stage 32 rows x 256 f32 (coalesced)
        int c = i * 256 + tid;
        int row = c >> 6, col4 = c & 63;
        float4 x = *reinterpret_cast<const float4*>(src + (size_t)row * EDIM + eh * 256 + col4 * 4);
        *reinterpret_cast<float4*>(&lds[row][col4 * 4]) = x;
      }
      __syncthreads();
#pragma unroll
      for (int i = 0; i < 4; i++) {       // emit 1024 half8 chunks / half
        int fl = i * 256 + tid;
        int lane = fl & 63, idx = fl >> 6;        // idx 0..15
        int est_l = idx & 7, rt_l = idx >> 3;     // est_l 0..7, rt_l 0..1
        int m15 = lane & 15, q4 = lane >> 4;
        const float* p = &lds[rt_l * 16 + m15][est_l * 32 + q4 * 8];
        float4 a = *reinterpret_cast<const float4*>(p);
        float4 bb = *reinterpret_cast<const float4*>(p + 4);
        *reinterpret_cast<half8*>(dst + ((size_t)(rt_l * 16 + eh * 8 + est_l)) * 512 + lane * 8) =
            cvt8(a, bb);
      }
    }
  } else {
    _Float16* dst = vf + ((size_t)(n * 64 + kt) * 32) * 512;
#pragma unroll
    for (int eh = 0; eh < 2; eh++) {
      if (eh) __syncthreads();
#pragma unroll
      for (int i = 0; i < 8; i++) {       // stage 32 rows x 256 f32
        int c = i * 256 + tid;
        int row = c >> 6, col4 = c & 63;
        float4 x = *reinterpret_cast<const float4*>(src + (size_t)row * EDIM + eh * 256 + col4 * 4);
        *reinterpret_cast<float4*>(&lds[row][col4 * 4]) = x;
      }
      __syncthreads();
#pragma unroll
      for (int i = 0; i < 4; i++) {       // emit transposed frag chunks
        int fl = i * 256 + tid;
        int etl = fl >> 6, ln = fl & 63;
        int m15 = ln & 15, q4 = ln >> 4;
        int e_local = etl * 16 + m15;
        half8 h;
#pragma unroll
        for (int j = 0; j < 8; j++) h[j] = (_Float16)lds[q4 * 8 + j][e_local];
        *reinterpret_cast<half8*>(dst + ((size_t)eh * 1024 + fl) * 8) = h;
      }
    }
  }
}

// ---------------------------------------------------------------------------
// Fused flash attention. Grid 512 = (n = blk&7, qt = blk>>3), 512 thr / 8 waves.
// BQ=32, BK=32, 64 K-tiles processed as 32 ping-pong pairs. Wave = (ks, es):
//   S: both 16-q strips x its 16-krow half x 128-e quarter.
//   softmax: 32 rows x 16 thr, 2 cols each; 4-plane combine.
//   PV: wave owns 64-e slice.
// Per tile: S(kcur) -> issue K(t+1) into the OTHER ping-pong set -> V prefetch
//   -> s_part -> b1 -> softmax -> b2 -> PV. No register copies; the K wait
//   lands at the next tile's S-MFMAs.
// LDS: 18432 + 2560 + 384 = 21376 B. __launch_bounds__(512,4): 2 blocks/CU.
// ---------------------------------------------------------------------------
__launch_bounds__(512, 4)
__global__ void attn_fused(const float* __restrict__ q, const _Float16* __restrict__ kf,
                           const _Float16* __restrict__ vf, float* __restrict__ out) {
  __shared__ float    s_part[4][32][36];   // 4 e-quarter partial scores
  __shared__ _Float16 p_lds[32][40];       // P fp16 (A-layout source)
  __shared__ float    m_lds[32], l_lds[32], a_lds[32];

  const int tid  = threadIdx.x;
  const int lane = tid & 63, w = tid >> 6;
  const int m15  = lane & 15, q4 = lane >> 4;
  const int n    = blockIdx.x & 7, qt = blockIdx.x >> 3;   // qt 0..63
  const int ks   = w & 1, es = w >> 1;

  if (tid < 32) { m_lds[tid] = -3.0e38f; l_lds[tid] = 0.0f; }

  // ---- Q fragments: inline fp32 gather + cvt (one-time; R8/R10/R12-verified).
  half8 qfr[2][4];
  {
    const float* qb = q + ((size_t)n * SEQ + qt * 32 + m15) * EDIM + es * 128 + q4 * 8;
#pragma unroll
    for (int s = 0; s < 2; s++)
#pragma unroll
      for (int i = 0; i < 4; i++) {
        const float* src = qb + (size_t)s * 16 * EDIM + i * 32;
        float4 a = *reinterpret_cast<const float4*>(src);
        float4 b = *reinterpret_cast<const float4*>(src + 4);
        qfr[s][i] = cvt8(a, b);
      }
  }

  floatx4 oacc[2][4];                       // [strip][et_local], 32 regs (acc)
#pragma unroll
  for (int s = 0; s < 2; s++)
#pragma unroll
    for (int j = 0; j < 4; j++) oacc[s][j] = (floatx4){0.f, 0.f, 0.f, 0.f};

  uint32_t koff = ((uint32_t)(n * 128 + ks) * 16 + es * 4) * 512 + (uint32_t)lane * 8;
  uint32_t voff = ((uint32_t)(n * 64) * 32 + w * 4) * 512 + (uint32_t)lane * 8;

  // ---- K ping-pong prologue: tile 0 into kfrA.
  half8 kfrA[4], kfrB[4];
#pragma unroll
  for (int i = 0; i < 4; i++)
    kfrA[i] = *reinterpret_cast<const half8*>(kf + koff + (uint32_t)i * 512);
  koff += 16384;                            // 2 rt * 16 est * 512

  block_sync_lds();                         // covers m/l init

  // One tile: S from kcur, prefetch next K into knxt, V prefetch, softmax, PV.
  auto tile = [&](half8 (&kcur)[4], half8 (&knxt)[4]) {
    floatx4 sacc[2];
    sacc[0] = (floatx4){0.f, 0.f, 0.f, 0.f};
    sacc[1] = (floatx4){0.f, 0.f, 0.f, 0.f};
    __builtin_amdgcn_s_setprio(1);
#pragma unroll
    for (int i = 0; i < 4; i++) {
      sacc[0] = __builtin_amdgcn_mfma_f32_16x16x32_f16(qfr[0][i], kcur[i], sacc[0], 0, 0, 0);
      sacc[1] = __builtin_amdgcn_mfma_f32_16x16x32_f16(qfr[1][i], kcur[i], sacc[1], 0, 0, 0);
    }
    __builtin_amdgcn_s_setprio(0);

    // issue next-tile K NOW (consumer = next tile's S-MFMAs): latency hides
    // under b1 + softmax + b2 + PV. Final iteration over-reads one tile into
    // the adjacent vf workspace region (in-bounds, never consumed).
#pragma unroll
    for (int i = 0; i < 4; i++)
      knxt[i] = *reinterpret_cast<const half8*>(kf + koff + (uint32_t)i * 512);
    koff += 16384;

    // V prefetch (this tile): consumer = PV below; hides under b1+softmax+b2.
    half8 vfr[4];
#pragma unroll
    for (int j = 0; j < 4; j++)
      vfr[j] = *reinterpret_cast<const half8*>(vf + voff + (uint32_t)j * 512);
    voff += 16384;                          // 32 et * 512

    // write partials (C-layout: row = q4*4+r, col = m15)
#pragma unroll
    for (int s = 0; s < 2; s++)
#pragma unroll
      for (int r = 0; r < 4; r++)
        s_part[es][s * 16 + q4 * 4 + r][ks * 16 + m15] = sacc[s][r];
    block_sync_lds();                       // b1

    // softmax: 32 rows x 16 threads, 2 cols each
    {
      const int r = tid >> 4, sub = tid & 15, c = sub * 2;
      float svx = s_part[0][r][c],     svy = s_part[0][r][c + 1];
#pragma unroll
      for (int pl = 1; pl < 4; pl++) { svx += s_part[pl][r][c]; svy += s_part[pl][r][c + 1]; }
      float mx = fmaxf(svx, svy);
#pragma unroll
      for (int o = 1; o < 16; o <<= 1) mx = fmaxf(mx, __shfl_xor(mx, o));
      const float mo = m_lds[r];
      const float mn = fmaxf(mo, mx);
      const float px = __expf(svx - mn), py = __expf(svy - mn);
      float rs = px + py;
#pragma unroll
      for (int o = 1; o < 16; o <<= 1) rs += __shfl_xor(rs, o);
      if (sub == 0) {
        const float al = __expf(mo - mn);
        a_lds[r] = al; m_lds[r] = mn; l_lds[r] = l_lds[r] * al + rs;
      }
      half2 ph; ph[0] = (_Float16)px; ph[1] = (_Float16)py;
      *reinterpret_cast<half2*>(&p_lds[r][c]) = ph;
    }
    block_sync_lds();                       // b2

    // PV phase: P A-frags from LDS, rescale, MFMA (vfr already in flight)
    half8 pfr[2];
    pfr[0] = *reinterpret_cast<const half8*>(&p_lds[m15][q4 * 8]);
    pfr[1] = *reinterpret_cast<const half8*>(&p_lds[16 + m15][q4 * 8]);
    {
      floatx4 al0 = *reinterpret_cast<floatx4*>(&a_lds[q4 * 4]);
      floatx4 al1 = *reinterpret_cast<floatx4*>(&a_lds[16 + q4 * 4]);
#pragma unroll
      for (int j = 0; j < 4; j++) { oacc[0][j] *= al0; oacc[1][j] *= al1; }
    }
    __builtin_amdgcn_s_setprio(1);
#pragma unroll
    for (int j = 0; j < 4; j++) {
      oacc[0][j] = __builtin_amdgcn_mfma_f32_16x16x32_f16(pfr[0], vfr[j], oacc[0][j], 0, 0, 0);
      oacc[1][j] = __builtin_amdgcn_mfma_f32_16x16x32_f16(pfr[1], vfr[j], oacc[1][j], 0, 0, 0);
    }
    __builtin_amdgcn_s_setprio(0);
  };

  for (int t = 0; t < 32; t++) {            // 32 ping-pong pairs = 64 tiles
    tile(kfrA, kfrB);
    tile(kfrB, kfrA);
  }

  // ---- epilogue: divide by l, store fp32 (l_lds final after last b2)
  const int q0 = qt * 32;
#pragma unroll
  for (int s = 0; s < 2; s++) {
    floatx4 lv = *reinterpret_cast<floatx4*>(&l_lds[s * 16 + q4 * 4]);
#pragma unroll
    for (int j = 0; j < 4; j++) {
      const int col = (w * 4 + j) * 16 + m15;
#pragma unroll
      for (int r = 0; r < 4; r++) {
        const int row = s * 16 + q4 * 4 + r;
        out[((size_t)n * SEQ + q0 + row) * EDIM + col] = oacc[s][j][r] / lv[r];
      }
    }
  }
}

// ---------------------------------------------------------------------------
// Fallback (ws too small): fp32 VALU attention, one block per query row.
// ---------------------------------------------------------------------------
__global__ void attn_fallback(const float* __restrict__ q, const float* __restrict__ k,
                              const float* __restrict__ v, float* __restrict__ out) {
  __shared__ float qrow[EDIM];
  __shared__ float sc[SEQ];
  __shared__ float red[16];
  const int tid = threadIdx.x;                    // 256
  const int n = blockIdx.x >> 11, qi = blockIdx.x & 2047;
  const int wv = tid >> 6, ln = tid & 63;
  const float* qp = q + ((size_t)n * SEQ + qi) * EDIM;
  for (int e = tid; e < EDIM; e += 256) qrow[e] = qp[e];
  __syncthreads();
  for (int kk = wv; kk < SEQ; kk += 4) {
    const float* kp = k + ((size_t)n * SEQ + kk) * EDIM;
    float s = 0.f;
    for (int e = ln; e < EDIM; e += 64) s = fmaf(qrow[e], kp[e], s);
    for (int o = 32; o > 0; o >>= 1) s += __shfl_down(s, o);
    if (ln == 0) sc[kk] = s;
  }
  __syncthreads();
  float mx = -3.0e38f;
  for (int kk = tid; kk < SEQ; kk += 256) mx = fmaxf(mx, sc[kk]);
  for (int o = 32; o > 0; o >>= 1) mx = fmaxf(mx, __shfl_down(mx, o));
  if (ln == 0) red[wv] = mx;
  __syncthreads();
  if (tid == 0) {
    float m2 = red[0];
    for (int i = 1; i < 4; i++) m2 = fmaxf(m2, red[i]);
    red[8] = m2;
  }
  __syncthreads();
  const float m = red[8];
  float ls = 0.f;
  for (int kk = tid; kk < SEQ; kk += 256) { float p = __expf(sc[kk] - m); sc[kk] = p; ls += p; }
  for (int o = 32; o > 0; o >>= 1) ls += __shfl_down(ls, o);
  if (ln == 0) red[wv] = ls;
  __syncthreads();
  if (tid == 0) { red[9] = red[0] + red[1] + red[2] + red[3]; }
  __syncthreads();
  const float linv = 1.f / red[9];
  for (int e = tid; e < EDIM; e += 256) {
    float acc = 0.f;
    const float* vp = v + ((size_t)n * SEQ) * EDIM + e;
    for (int kk = 0; kk < SEQ; kk++) acc = fmaf(sc[kk], vp[(size_t)kk * EDIM], acc);
    out[((size_t)n * SEQ + qi) * EDIM + e] = acc * linv;
  }
}

extern "C" void kernel_launch(void* const* d_in, const int* in_sizes, int n_in,
                              void* d_out, int out_size, void* d_ws, size_t ws_size,
                              hipStream_t stream) {
  const float* q = (const float*)d_in[0];
  const float* k = (const float*)d_in[1];
  const float* v = (const float*)d_in[2];
  float* out = (float*)d_out;
  const size_t need = 2 * NE * sizeof(_Float16);   // 33.6 MB (K + V frags)
  if (ws_size >= need) {
    _Float16* kf = (_Float16*)d_ws;
    _Float16* vf = kf + NE;
    make_frags<<<1024, 256, 0, stream>>>(k, v, kf, vf);
    attn_fused<<<512, 512, 0, stream>>>(q, kf, vf, out);
  } else {
    attn_fallback<<<16384, 256, 0, stream>>>(q, k, v, out);
  }
}

// Round 8
// 227.474 us; speedup vs baseline: 1.4183x; 1.4183x over previous
//
#include <hip/hip_runtime.h>
#include <stdint.h>

// ---------------------------------------------------------------------------
// Attention: out = softmax(Q K^T) V,  N=8, S=2048, E=512, fp32 in/out.
// R14 = single-variable experiment: R9's PROVEN attn loop (118us; K top-of-
// loop, V prefetch after S, setprio, BK=32) byte-identical, with ONLY the Q
// source changed: inline fp32 gather in the prologue (replaces the Q pre-pass
// segment). Pre-pass is K+V only (R10's proven 1024-block make_frags).
// R13 post-mortem: ALL register K-prefetch variants regress — ping-pong
// pushed live regs past the 128 budget -> scratch spill (FETCH +12MB,
// MfmaUtil 12.6%, 224us). K latency is already hidden by the other resident
// block per CU; the R9 loop's register windows must not be widened.
// ---------------------------------------------------------------------------

typedef __attribute__((ext_vector_type(8))) _Float16 half8;   // MFMA A/B frag
typedef __attribute__((ext_vector_type(2))) _Float16 half2;
typedef __attribute__((ext_vector_type(4))) float    floatx4; // MFMA C/D frag

#define NBATCH 8
#define SEQ    2048
#define EDIM   512
static constexpr size_t NE = (size_t)NBATCH * SEQ * EDIM;  // 8388608 elems/tensor

// Barrier WITHOUT vmcnt drain: LDS ordering only; global loads in flight stay
// in flight (their consumers get compiler-inserted vmcnt waits).
__device__ __forceinline__ void block_sync_lds() {
  asm volatile("s_waitcnt lgkmcnt(0)\n\ts_barrier" ::: "memory");
}

__device__ __forceinline__ half8 cvt8(float4 a, float4 b) {
  half8 h;
  h[0] = (_Float16)a.x; h[1] = (_Float16)a.y; h[2] = (_Float16)a.z; h[3] = (_Float16)a.w;
  h[4] = (_Float16)b.x; h[5] = (_Float16)b.y; h[6] = (_Float16)b.z; h[7] = (_Float16)b.w;
  return h;
}

// ---------------------------------------------------------------------------
// Fragment layout contract (A/B-frag 16x16x32): lane l holds
//   [dim16 = l&15][k = (l>>4)*8 + j].
//  K: kf[((n*128 + rt)*16 + est)*512 + lane*8 + j]   (rt = row>>4, est = e>>5)
//  V: vf[((n*64 + kt)*32 + et)*512 + lane*8 + j]     (kt = krow>>5, et = e>>4,
//        dim16 = e-col, k = krow within 32-tile)
// ---------------------------------------------------------------------------

// --- pre-pass: 1024 blocks = 2 segments (K,V) x 8 n x 64 row-tiles. (R10-proven)
__global__ void make_frags(const float* __restrict__ k, const float* __restrict__ v,
                           _Float16* __restrict__ kf, _Float16* __restrict__ vf) {
  __shared__ float lds[32][260];
  const int tid = threadIdx.x;
  const int seg = blockIdx.x >> 9;        // 0=K, 1=V
  const int b   = blockIdx.x & 511;       // 8 n x 64 kt
  const int n = b >> 6, kt = b & 63;
  const float* src = (seg == 0 ? k : v) + ((size_t)n * SEQ + kt * 32) * EDIM;

  if (seg == 0) {
    _Float16* dst = kf + ((size_t)(n * 128 + kt * 2) * 16) * 512;
#pragma unroll
    for (int eh = 0; eh < 2; eh++) {
      if (eh) __syncthreads();
#pragma unroll
      for (int i = 0; i < 8; i++) {       // stage 32 rows x 256 f32 (coalesced)
        int c = i * 256 + tid;
        int row = c >> 6, col4 = c & 63;
        float4 x = *reinterpret_cast<const float4*>(src + (size_t)row * EDIM + eh * 256 + col4 * 4);
        *reinterpret_cast<float4*>(&lds[row][col4 * 4]) = x;
      }
      __syncthreads();
#pragma unroll
      for (int i = 0; i < 4; i++) {       // emit 1024 half8 chunks / half
        int fl = i * 256 + tid;
        int lane = fl & 63, idx = fl >> 6;        // idx 0..15
        int est_l = idx & 7, rt_l = idx >> 3;     // est_l 0..7, rt_l 0..1
        int m15 = lane & 15, q4 = lane >> 4;
        const float* p = &lds[rt_l * 16 + m15][est_l * 32 + q4 * 8];
        float4 a = *reinterpret_cast<const float4*>(p);
        float4 bb = *reinterpret_cast<const float4*>(p + 4);
        *reinterpret_cast<half8*>(dst + ((size_t)(rt_l * 16 + eh * 8 + est_l)) * 512 + lane * 8) =
            cvt8(a, bb);
      }
    }
  } else {
    _Float16* dst = vf + ((size_t)(n * 64 + kt) * 32) * 512;
#pragma unroll
    for (int eh = 0; eh < 2; eh++) {
      if (eh) __syncthreads();
#pragma unroll
      for (int i = 0; i < 8; i++) {       // stage 32 rows x 256 f32
        int c = i * 256 + tid;
        int row = c >> 6, col4 = c & 63;
        float4 x = *reinterpret_cast<const float4*>(src + (size_t)row * EDIM + eh * 256 + col4 * 4);
        *reinterpret_cast<float4*>(&lds[row][col4 * 4]) = x;
      }
      __syncthreads();
#pragma unroll
      for (int i = 0; i < 4; i++) {       // emit transposed frag chunks
        int fl = i * 256 + tid;
        int etl = fl >> 6, ln = fl & 63;
        int m15 = ln & 15, q4 = ln >> 4;
        int e_local = etl * 16 + m15;
        half8 h;
#pragma unroll
        for (int j = 0; j < 8; j++) h[j] = (_Float16)lds[q4 * 8 + j][e_local];
        *reinterpret_cast<half8*>(dst + ((size_t)eh * 1024 + fl) * 8) = h;
      }
    }
  }
}

// ---------------------------------------------------------------------------
// Fused flash attention — R9's proven loop. Grid 512 = (n, qt), 512 thr.
// BQ=32, BK=32, 64 K-tiles. Wave = (ks = w&1, es = w>>1):
//   S: both 16-q strips x its 16-krow half x 128-e quarter (K frags no-dup).
//   softmax: 32 rows x 16 thr, 2 cols each; 4-plane combine.
//   PV: wave owns 64-e slice (et = w*4..w*4+3).
// Per tile: Kload -> S -> V prefetch -> s_part -> b1 -> softmax -> b2 -> PV.
// LDS: 18432 + 2560 + 384 = 21376 B. __launch_bounds__(512,4): 2 blocks/CU;
// transient K/V windows identical to R9 (kfr dies at S-MFMA, vfr born after).
// ---------------------------------------------------------------------------
__launch_bounds__(512, 4)
__global__ void attn_fused(const float* __restrict__ q, const _Float16* __restrict__ kf,
                           const _Float16* __restrict__ vf, float* __restrict__ out) {
  __shared__ float    s_part[4][32][36];   // 4 e-quarter partial scores
  __shared__ _Float16 p_lds[32][40];       // P fp16 (A-layout source)
  __shared__ float    m_lds[32], l_lds[32], a_lds[32];

  const int tid  = threadIdx.x;
  const int lane = tid & 63, w = tid >> 6;
  const int m15  = lane & 15, q4 = lane >> 4;
  const int n    = blockIdx.x & 7, qt = blockIdx.x >> 3;   // qt 0..63
  const int ks   = w & 1, es = w >> 1;

  if (tid < 32) { m_lds[tid] = -3.0e38f; l_lds[tid] = 0.0f; }

  // ---- Q fragments: inline fp32 gather + cvt (ONE-TIME prologue; transients
  // die before the loop). row = qt*32 + s*16 + m15, col = es*128 + i*32 + q4*8.
  half8 qfr[2][4];
  {
    const float* qb = q + ((size_t)n * SEQ + qt * 32 + m15) * EDIM + es * 128 + q4 * 8;
#pragma unroll
    for (int s = 0; s < 2; s++)
#pragma unroll
      for (int i = 0; i < 4; i++) {
        const float* src = qb + (size_t)s * 16 * EDIM + i * 32;
        float4 a = *reinterpret_cast<const float4*>(src);
        float4 b = *reinterpret_cast<const float4*>(src + 4);
        qfr[s][i] = cvt8(a, b);
      }
  }

  floatx4 oacc[2][4];                       // [strip][et_local], 32 regs (acc)
#pragma unroll
  for (int s = 0; s < 2; s++)
#pragma unroll
    for (int j = 0; j < 4; j++) oacc[s][j] = (floatx4){0.f, 0.f, 0.f, 0.f};

  uint32_t koff = ((uint32_t)(n * 128 + ks) * 16 + es * 4) * 512 + (uint32_t)lane * 8;
  uint32_t voff = ((uint32_t)(n * 64) * 32 + w * 4) * 512 + (uint32_t)lane * 8;

  block_sync_lds();                         // covers m/l init

  for (int t = 0; t < 64; t++) {
    // ---- S phase: K frags transient, direct global->reg (1KB coalesced each)
    half8 kfr[4];
#pragma unroll
    for (int i = 0; i < 4; i++)
      kfr[i] = *reinterpret_cast<const half8*>(kf + koff + (uint32_t)i * 512);
    koff += 16384;                          // 2 rt * 16 est * 512

    floatx4 sacc[2];
    sacc[0] = (floatx4){0.f, 0.f, 0.f, 0.f};
    sacc[1] = (floatx4){0.f, 0.f, 0.f, 0.f};
    __builtin_amdgcn_s_setprio(1);
#pragma unroll
    for (int i = 0; i < 4; i++) {
      sacc[0] = __builtin_amdgcn_mfma_f32_16x16x32_f16(qfr[0][i], kfr[i], sacc[0], 0, 0, 0);
      sacc[1] = __builtin_amdgcn_mfma_f32_16x16x32_f16(qfr[1][i], kfr[i], sacc[1], 0, 0, 0);
    }
    __builtin_amdgcn_s_setprio(0);

    // ---- V prefetch (this tile): issue NOW so the L2 latency hides under
    // b1 + softmax + b2. kfr dies above, vfr born here: no peak-VGPR change.
    half8 vfr[4];
#pragma unroll
    for (int j = 0; j < 4; j++)
      vfr[j] = *reinterpret_cast<const half8*>(vf + voff + (uint32_t)j * 512);
    voff += 16384;                          // 32 et * 512

    // write partials (C-layout: row = q4*4+r, col = m15)
#pragma unroll
    for (int s = 0; s < 2; s++)
#pragma unroll
      for (int r = 0; r < 4; r++)
        s_part[es][s * 16 + q4 * 4 + r][ks * 16 + m15] = sacc[s][r];
    block_sync_lds();                       // b1

    // ---- softmax: 32 rows x 16 threads, 2 cols each
    {
      const int r = tid >> 4, sub = tid & 15, c = sub * 2;
      float svx = s_part[0][r][c],     svy = s_part[0][r][c + 1];
#pragma unroll
      for (int pl = 1; pl < 4; pl++) { svx += s_part[pl][r][c]; svy += s_part[pl][r][c + 1]; }
      float mx = fmaxf(svx, svy);
#pragma unroll
      for (int o = 1; o < 16; o <<= 1) mx = fmaxf(mx, __shfl_xor(mx, o));
      const float mo = m_lds[r];
      const float mn = fmaxf(mo, mx);
      const float px = __expf(svx - mn), py = __expf(svy - mn);
      float rs = px + py;
#pragma unroll
      for (int o = 1; o < 16; o <<= 1) rs += __shfl_xor(rs, o);
      if (sub == 0) {
        const float al = __expf(mo - mn);
        a_lds[r] = al; m_lds[r] = mn; l_lds[r] = l_lds[r] * al + rs;
      }
      half2 ph; ph[0] = (_Float16)px; ph[1] = (_Float16)py;
      *reinterpret_cast<half2*>(&p_lds[r][c]) = ph;
    }
    block_sync_lds();                       // b2

    // ---- PV phase: P A-frags from LDS, rescale, MFMA (vfr already in flight)
    half8 pfr[2];
    pfr[0] = *reinterpret_cast<const half8*>(&p_lds[m15][q4 * 8]);
    pfr[1] = *reinterpret_cast<const half8*>(&p_lds[16 + m15][q4 * 8]);
    {
      floatx4 al0 = *reinterpret_cast<floatx4*>(&a_lds[q4 * 4]);
      floatx4 al1 = *reinterpret_cast<floatx4*>(&a_lds[16 + q4 * 4]);
#pragma unroll
      for (int j = 0; j < 4; j++) { oacc[0][j] *= al0; oacc[1][j] *= al1; }
    }
    __builtin_amdgcn_s_setprio(1);
#pragma unroll
    for (int j = 0; j < 4; j++) {
      oacc[0][j] = __builtin_amdgcn_mfma_f32_16x16x32_f16(pfr[0], vfr[j], oacc[0][j], 0, 0, 0);
      oacc[1][j] = __builtin_amdgcn_mfma_f32_16x16x32_f16(pfr[1], vfr[j], oacc[1][j], 0, 0, 0);
    }
    __builtin_amdgcn_s_setprio(0);
  }

  // ---- epilogue: divide by l, store fp32 (l_lds final after last b2)
  const int q0 = qt * 32;
#pragma unroll
  for (int s = 0; s < 2; s++) {
    floatx4 lv = *reinterpret_cast<floatx4*>(&l_lds[s * 16 + q4 * 4]);
#pragma unroll
    for (int j = 0; j < 4; j++) {
      const int col = (w * 4 + j) * 16 + m15;
#pragma unroll
      for (int r = 0; r < 4; r++) {
        const int row = s * 16 + q4 * 4 + r;
        out[((size_t)n * SEQ + q0 + row) * EDIM + col] = oacc[s][j][r] / lv[r];
      }
    }
  }
}

// ---------------------------------------------------------------------------
// Fallback (ws too small): fp32 VALU attention, one block per query row.
// ---------------------------------------------------------------------------
__global__ void attn_fallback(const float* __restrict__ q, const float* __restrict__ k,
                              const float* __restrict__ v, float* __restrict__ out) {
  __shared__ float qrow[EDIM];
  __shared__ float sc[SEQ];
  __shared__ float red[16];
  const int tid = threadIdx.x;                    // 256
  const int n = blockIdx.x >> 11, qi = blockIdx.x & 2047;
  const int wv = tid >> 6, ln = tid & 63;
  const float* qp = q + ((size_t)n * SEQ + qi) * EDIM;
  for (int e = tid; e < EDIM; e += 256) qrow[e] = qp[e];
  __syncthreads();
  for (int kk = wv; kk < SEQ; kk += 4) {
    const float* kp = k + ((size_t)n * SEQ + kk) * EDIM;
    float s = 0.f;
    for (int e = ln; e < EDIM; e += 64) s = fmaf(qrow[e], kp[e], s);
    for (int o = 32; o > 0; o >>= 1) s += __shfl_down(s, o);
    if (ln == 0) sc[kk] = s;
  }
  __syncthreads();
  float mx = -3.0e38f;
  for (int kk = tid; kk < SEQ; kk += 256) mx = fmaxf(mx, sc[kk]);
  for (int o = 32; o > 0; o >>= 1) mx = fmaxf(mx, __shfl_down(mx, o));
  if (ln == 0) red[wv] = mx;
  __syncthreads();
  if (tid == 0) {
    float m2 = red[0];
    for (int i = 1; i < 4; i++) m2 = fmaxf(m2, red[i]);
    red[8] = m2;
  }
  __syncthreads();
  const float m = red[8];
  float ls = 0.f;
  for (int kk = tid; kk < SEQ; kk += 256) { float p = __expf(sc[kk] - m); sc[kk] = p; ls += p; }
  for (int o = 32; o > 0; o >>= 1) ls += __shfl_down(ls, o);
  if (ln == 0) red[wv] = ls;
  __syncthreads();
  if (tid == 0) { red[9] = red[0] + red[1] + red[2] + red[3]; }
  __syncthreads();
  const float linv = 1.f / red[9];
  for (int e = tid; e < EDIM; e += 256) {
    float acc = 0.f;
    const float* vp = v + ((size_t)n * SEQ) * EDIM + e;
    for (int kk = 0; kk < SEQ; kk++) acc = fmaf(sc[kk], vp[(size_t)kk * EDIM], acc);
    out[((size_t)n * SEQ + qi) * EDIM + e] = acc * linv;
  }
}

extern "C" void kernel_launch(void* const* d_in, const int* in_sizes, int n_in,
                              void* d_out, int out_size, void* d_ws, size_t ws_size,
                              hipStream_t stream) {
  const float* q = (const float*)d_in[0];
  const float* k = (const float*)d_in[1];
  const float* v = (const float*)d_in[2];
  float* out = (float*)d_out;
  const size_t need = 2 * NE * sizeof(_Float16);   // 33.6 MB (K + V frags)
  if (ws_size >= need) {
    _Float16* kf = (_Float16*)d_ws;
    _Float16* vf = kf + NE;
    make_frags<<<1024, 256, 0, stream>>>(k, v, kf, vf);
    attn_fused<<<512, 512, 0, stream>>>(q, kf, vf, out);
  } else {
    attn_fallback<<<16384, 256, 0, stream>>>(q, k, v, out);
  }
}

// Round 9
// 224.027 us; speedup vs baseline: 1.4402x; 1.0154x over previous
//
#include <hip/hip_runtime.h>
#include <stdint.h>

// ---------------------------------------------------------------------------
// Attention: out = softmax(Q K^T) V,  N=8, S=2048, E=512, fp32 in/out.
// R15 = R14 with the Q prologue gather COALESCED via LDS staging (reuses the
// s_part allocation; zero LDS growth; loop body byte-identical to R9/R14).
// R14 attribution: Q-inline scattered fp32 gather cost +14us in-kernel
// (32 lines/instr, cold HBM) but removed 512 pre-pass blocks (-26us gap) ->
// net win. This round removes the scatter: stage 4 chunks of 32x128 f32
// coalesced into LDS, gather frags from LDS (528B row stride, 16B-aligned,
// ~2-way bank aliasing). Pre-pass stays K+V only (R10-proven, 1024 blocks).
// Standing lessons: do NOT widen loop-resident register windows (R13 spill),
// do NOT change tile geometry (R12 bank conflicts), K latency already hidden
// by the co-resident block (R10/R13).
// ---------------------------------------------------------------------------

typedef __attribute__((ext_vector_type(8))) _Float16 half8;   // MFMA A/B frag
typedef __attribute__((ext_vector_type(2))) _Float16 half2;
typedef __attribute__((ext_vector_type(4))) float    floatx4; // MFMA C/D frag

#define NBATCH 8
#define SEQ    2048
#define EDIM   512
static constexpr size_t NE = (size_t)NBATCH * SEQ * EDIM;  // 8388608 elems/tensor

// Barrier WITHOUT vmcnt drain: LDS ordering only; global loads in flight stay
// in flight (their consumers get compiler-inserted vmcnt waits).
__device__ __forceinline__ void block_sync_lds() {
  asm volatile("s_waitcnt lgkmcnt(0)\n\ts_barrier" ::: "memory");
}

__device__ __forceinline__ half8 cvt8(float4 a, float4 b) {
  half8 h;
  h[0] = (_Float16)a.x; h[1] = (_Float16)a.y; h[2] = (_Float16)a.z; h[3] = (_Float16)a.w;
  h[4] = (_Float16)b.x; h[5] = (_Float16)b.y; h[6] = (_Float16)b.z; h[7] = (_Float16)b.w;
  return h;
}

// ---------------------------------------------------------------------------
// Fragment layout contract (A/B-frag 16x16x32): lane l holds
//   [dim16 = l&15][k = (l>>4)*8 + j].
//  K: kf[((n*128 + rt)*16 + est)*512 + lane*8 + j]   (rt = row>>4, est = e>>5)
//  V: vf[((n*64 + kt)*32 + et)*512 + lane*8 + j]     (kt = krow>>5, et = e>>4,
//        dim16 = e-col, k = krow within 32-tile)
// ---------------------------------------------------------------------------

// --- pre-pass: 1024 blocks = 2 segments (K,V) x 8 n x 64 row-tiles. (R10-proven)
__global__ void make_frags(const float* __restrict__ k, const float* __restrict__ v,
                           _Float16* __restrict__ kf, _Float16* __restrict__ vf) {
  __shared__ float lds[32][260];
  const int tid = threadIdx.x;
  const int seg = blockIdx.x >> 9;        // 0=K, 1=V
  const int b   = blockIdx.x & 511;       // 8 n x 64 kt
  const int n = b >> 6, kt = b & 63;
  const float* src = (seg == 0 ? k : v) + ((size_t)n * SEQ + kt * 32) * EDIM;

  if (seg == 0) {
    _Float16* dst = kf + ((size_t)(n * 128 + kt * 2) * 16) * 512;
#pragma unroll
    for (int eh = 0; eh < 2; eh++) {
      if (eh) __syncthreads();
#pragma unroll
      for (int i = 0; i < 8; i++) {       // stage 32 rows x 256 f32 (coalesced)
        int c = i * 256 + tid;
        int row = c >> 6, col4 = c & 63;
        float4 x = *reinterpret_cast<const float4*>(src + (size_t)row * EDIM + eh * 256 + col4 * 4);
        *reinterpret_cast<float4*>(&lds[row][col4 * 4]) = x;
      }
      __syncthreads();
#pragma unroll
      for (int i = 0; i < 4; i++) {       // emit 1024 half8 chunks / half
        int fl = i * 256 + tid;
        int lane = fl & 63, idx = fl >> 6;        // idx 0..15
        int est_l = idx & 7, rt_l = idx >> 3;     // est_l 0..7, rt_l 0..1
        int m15 = lane & 15, q4 = lane >> 4;
        const float* p = &lds[rt_l * 16 + m15][est_l * 32 + q4 * 8];
        float4 a = *reinterpret_cast<const float4*>(p);
        float4 bb = *reinterpret_cast<const float4*>(p + 4);
        *reinterpret_cast<half8*>(dst + ((size_t)(rt_l * 16 + eh * 8 + est_l)) * 512 + lane * 8) =
            cvt8(a, bb);
      }
    }
  } else {
    _Float16* dst = vf + ((size_t)(n * 64 + kt) * 32) * 512;
#pragma unroll
    for (int eh = 0; eh < 2; eh++) {
      if (eh) __syncthreads();
#pragma unroll
      for (int i = 0; i < 8; i++) {       // stage 32 rows x 256 f32
        int c = i * 256 + tid;
        int row = c >> 6, col4 = c & 63;
        float4 x = *reinterpret_cast<const float4*>(src + (size_t)row * EDIM + eh * 256 + col4 * 4);
        *reinterpret_cast<float4*>(&lds[row][col4 * 4]) = x;
      }
      __syncthreads();
#pragma unroll
      for (int i = 0; i < 4; i++) {       // emit transposed frag chunks
        int fl = i * 256 + tid;
        int etl = fl >> 6, ln = fl & 63;
        int m15 = ln & 15, q4 = ln >> 4;
        int e_local = etl * 16 + m15;
        half8 h;
#pragma unroll
        for (int j = 0; j < 8; j++) h[j] = (_Float16)lds[q4 * 8 + j][e_local];
        *reinterpret_cast<half8*>(dst + ((size_t)eh * 1024 + fl) * 8) = h;
      }
    }
  }
}

// ---------------------------------------------------------------------------
// Fused flash attention — R9's proven loop. Grid 512 = (n, qt), 512 thr.
// BQ=32, BK=32, 64 K-tiles. Wave = (ks = w&1, es = w>>1):
//   S: both 16-q strips x its 16-krow half x 128-e quarter (K frags no-dup).
//   softmax: 32 rows x 16 thr, 2 cols each; 4-plane combine.
//   PV: wave owns 64-e slice (et = w*4..w*4+3).
// Per tile: Kload -> S -> V prefetch -> s_part -> b1 -> softmax -> b2 -> PV.
// Prologue: Q staged coalesced through s_part's LDS (4 chunks of 32x128 f32,
// 16.9KB < 18.4KB), then per-wave frag gather from LDS.
// LDS: 18432 + 2560 + 384 = 21376 B. __launch_bounds__(512,4): 2 blocks/CU.
// ---------------------------------------------------------------------------
__launch_bounds__(512, 4)
__global__ void attn_fused(const float* __restrict__ q, const _Float16* __restrict__ kf,
                           const _Float16* __restrict__ vf, float* __restrict__ out) {
  __shared__ float    s_part[4][32][36];   // 4 e-quarter partial scores
  __shared__ _Float16 p_lds[32][40];       // P fp16 (A-layout source)
  __shared__ float    m_lds[32], l_lds[32], a_lds[32];

  const int tid  = threadIdx.x;
  const int lane = tid & 63, w = tid >> 6;
  const int m15  = lane & 15, q4 = lane >> 4;
  const int n    = blockIdx.x & 7, qt = blockIdx.x >> 3;   // qt 0..63
  const int ks   = w & 1, es = w >> 1;

  if (tid < 32) { m_lds[tid] = -3.0e38f; l_lds[tid] = 0.0f; }

  // ---- Q fragments via COALESCED LDS staging (prologue; reuses s_part).
  // 4 chunks of 32 rows x 128 f32 cols; each chunk consumed by the 2 waves
  // with es == chunk. Stage: consecutive lanes -> consecutive addresses.
  // Gather: row stride 132 f32 = 528 B (16B-aligned; banks spread 4/row).
  half8 qfr[2][4];
  {
    float (*qstage)[132] = reinterpret_cast<float (*)[132]>(&s_part[0][0][0]);  // 16896 B
    const float* qbase = q + ((size_t)n * SEQ + qt * 32) * EDIM;
#pragma unroll 1
    for (int ec = 0; ec < 4; ec++) {
#pragma unroll
      for (int it = 0; it < 2; it++) {     // 1024 float4 per chunk, 2/thread
        int c = it * 512 + tid;
        int row = c >> 5, col4 = c & 31;   // 32 rows x 32 float4
        float4 x = *reinterpret_cast<const float4*>(
            qbase + (size_t)row * EDIM + ec * 128 + col4 * 4);
        *reinterpret_cast<float4*>(&qstage[row][col4 * 4]) = x;
      }
      __syncthreads();
      if (es == ec) {
#pragma unroll
        for (int s = 0; s < 2; s++)
#pragma unroll
          for (int i = 0; i < 4; i++) {
            const float* p = &qstage[s * 16 + m15][i * 32 + q4 * 8];
            float4 a = *reinterpret_cast<const float4*>(p);
            float4 b = *reinterpret_cast<const float4*>(p + 4);
            qfr[s][i] = cvt8(a, b);        // col = es*128 + i*32 + q4*8 + j
          }
      }
      __syncthreads();
    }
  }

  floatx4 oacc[2][4];                       // [strip][et_local], 32 regs (acc)
#pragma unroll
  for (int s = 0; s < 2; s++)
#pragma unroll
    for (int j = 0; j < 4; j++) oacc[s][j] = (floatx4){0.f, 0.f, 0.f, 0.f};

  uint32_t koff = ((uint32_t)(n * 128 + ks) * 16 + es * 4) * 512 + (uint32_t)lane * 8;
  uint32_t voff = ((uint32_t)(n * 64) * 32 + w * 4) * 512 + (uint32_t)lane * 8;

  block_sync_lds();                         // covers m/l init + staging reuse

  for (int t = 0; t < 64; t++) {
    // ---- S phase: K frags transient, direct global->reg (1KB coalesced each)
    half8 kfr[4];
#pragma unroll
    for (int i = 0; i < 4; i++)
      kfr[i] = *reinterpret_cast<const half8*>(kf + koff + (uint32_t)i * 512);
    koff += 16384;                          // 2 rt * 16 est * 512

    floatx4 sacc[2];
    sacc[0] = (floatx4){0.f, 0.f, 0.f, 0.f};
    sacc[1] = (floatx4){0.f, 0.f, 0.f, 0.f};
    __builtin_amdgcn_s_setprio(1);
#pragma unroll
    for (int i = 0; i < 4; i++) {
      sacc[0] = __builtin_amdgcn_mfma_f32_16x16x32_f16(qfr[0][i], kfr[i], sacc[0], 0, 0, 0);
      sacc[1] = __builtin_amdgcn_mfma_f32_16x16x32_f16(qfr[1][i], kfr[i], sacc[1], 0, 0, 0);
    }
    __builtin_amdgcn_s_setprio(0);

    // ---- V prefetch (this tile): issue NOW so the L2 latency hides under
    // b1 + softmax + b2. kfr dies above, vfr born here: no peak-VGPR change.
    half8 vfr[4];
#pragma unroll
    for (int j = 0; j < 4; j++)
      vfr[j] = *reinterpret_cast<const half8*>(vf + voff + (uint32_t)j * 512);
    voff += 16384;                          // 32 et * 512

    // write partials (C-layout: row = q4*4+r, col = m15)
#pragma unroll
    for (int s = 0; s < 2; s++)
#pragma unroll
      for (int r = 0; r < 4; r++)
        s_part[es][s * 16 + q4 * 4 + r][ks * 16 + m15] = sacc[s][r];
    block_sync_lds();                       // b1

    // ---- softmax: 32 rows x 16 threads, 2 cols each
    {
      const int r = tid >> 4, sub = tid & 15, c = sub * 2;
      float svx = s_part[0][r][c],     svy = s_part[0][r][c + 1];
#pragma unroll
      for (int pl = 1; pl < 4; pl++) { svx += s_part[pl][r][c]; svy += s_part[pl][r][c + 1]; }
      float mx = fmaxf(svx, svy);
#pragma unroll
      for (int o = 1; o < 16; o <<= 1) mx = fmaxf(mx, __shfl_xor(mx, o));
      const float mo = m_lds[r];
      const float mn = fmaxf(mo, mx);
      const float px = __expf(svx - mn), py = __expf(svy - mn);
      float rs = px + py;
#pragma unroll
      for (int o = 1; o < 16; o <<= 1) rs += __shfl_xor(rs, o);
      if (sub == 0) {
        const float al = __expf(mo - mn);
        a_lds[r] = al; m_lds[r] = mn; l_lds[r] = l_lds[r] * al + rs;
      }
      half2 ph; ph[0] = (_Float16)px; ph[1] = (_Float16)py;
      *reinterpret_cast<half2*>(&p_lds[r][c]) = ph;
    }
    block_sync_lds();                       // b2

    // ---- PV phase: P A-frags from LDS, rescale, MFMA (vfr already in flight)
    half8 pfr[2];
    pfr[0] = *reinterpret_cast<const half8*>(&p_lds[m15][q4 * 8]);
    pfr[1] = *reinterpret_cast<const half8*>(&p_lds[16 + m15][q4 * 8]);
    {
      floatx4 al0 = *reinterpret_cast<floatx4*>(&a_lds[q4 * 4]);
      floatx4 al1 = *reinterpret_cast<floatx4*>(&a_lds[16 + q4 * 4]);
#pragma unroll
      for (int j = 0; j < 4; j++) { oacc[0][j] *= al0; oacc[1][j] *= al1; }
    }
    __builtin_amdgcn_s_setprio(1);
#pragma unroll
    for (int j = 0; j < 4; j++) {
      oacc[0][j] = __builtin_amdgcn_mfma_f32_16x16x32_f16(pfr[0], vfr[j], oacc[0][j], 0, 0, 0);
      oacc[1][j] = __builtin_amdgcn_mfma_f32_16x16x32_f16(pfr[1], vfr[j], oacc[1][j], 0, 0, 0);
    }
    __builtin_amdgcn_s_setprio(0);
  }

  // ---- epilogue: divide by l, store fp32 (l_lds final after last b2)
  const int q0 = qt * 32;
#pragma unroll
  for (int s = 0; s < 2; s++) {
    floatx4 lv = *reinterpret_cast<floatx4*>(&l_lds[s * 16 + q4 * 4]);
#pragma unroll
    for (int j = 0; j < 4; j++) {
      const int col = (w * 4 + j) * 16 + m15;
#pragma unroll
      for (int r = 0; r < 4; r++) {
        const int row = s * 16 + q4 * 4 + r;
        out[((size_t)n * SEQ + q0 + row) * EDIM + col] = oacc[s][j][r] / lv[r];
      }
    }
  }
}

// ---------------------------------------------------------------------------
// Fallback (ws too small): fp32 VALU attention, one block per query row.
// ---------------------------------------------------------------------------
__global__ void attn_fallback(const float* __restrict__ q, const float* __restrict__ k,
                              const float* __restrict__ v, float* __restrict__ out) {
  __shared__ float qrow[EDIM];
  __shared__ float sc[SEQ];
  __shared__ float red[16];
  const int tid = threadIdx.x;                    // 256
  const int n = blockIdx.x >> 11, qi = blockIdx.x & 2047;
  const int wv = tid >> 6, ln = tid & 63;
  const float* qp = q + ((size_t)n * SEQ + qi) * EDIM;
  for (int e = tid; e < EDIM; e += 256) qrow[e] = qp[e];
  __syncthreads();
  for (int kk = wv; kk < SEQ; kk += 4) {
    const float* kp = k + ((size_t)n * SEQ + kk) * EDIM;
    float s = 0.f;
    for (int e = ln; e < EDIM; e += 64) s = fmaf(qrow[e], kp[e], s);
    for (int o = 32; o > 0; o >>= 1) s += __shfl_down(s, o);
    if (ln == 0) sc[kk] = s;
  }
  __syncthreads();
  float mx = -3.0e38f;
  for (int kk = tid; kk < SEQ; kk += 256) mx = fmaxf(mx, sc[kk]);
  for (int o = 32; o > 0; o >>= 1) mx = fmaxf(mx, __shfl_down(mx, o));
  if (ln == 0) red[wv] = mx;
  __syncthreads();
  if (tid == 0) {
    float m2 = red[0];
    for (int i = 1; i < 4; i++) m2 = fmaxf(m2, red[i]);
    red[8] = m2;
  }
  __syncthreads();
  const float m = red[8];
  float ls = 0.f;
  for (int kk = tid; kk < SEQ; kk += 256) { float p = __expf(sc[kk] - m); sc[kk] = p; ls += p; }
  for (int o = 32; o > 0; o >>= 1) ls += __shfl_down(ls, o);
  if (ln == 0) red[wv] = ls;
  __syncthreads();
  if (tid == 0) { red[9] = red[0] + red[1] + red[2] + red[3]; }
  __syncthreads();
  const float linv = 1.f / red[9];
  for (int e = tid; e < EDIM; e += 256) {
    float acc = 0.f;
    const float* vp = v + ((size_t)n * SEQ) * EDIM + e;
    for (int kk = 0; kk < SEQ; kk++) acc = fmaf(sc[kk], vp[(size_t)kk * EDIM], acc);
    out[((size_t)n * SEQ + qi) * EDIM + e] = acc * linv;
  }
}

extern "C" void kernel_launch(void* const* d_in, const int* in_sizes, int n_in,
                              void* d_out, int out_size, void* d_ws, size_t ws_size,
                              hipStream_t stream) {
  const float* q = (const float*)d_in[0];
  const float* k = (const float*)d_in[1];
  const float* v = (const float*)d_in[2];
  float* out = (float*)d_out;
  const size_t need = 2 * NE * sizeof(_Float16);   // 33.6 MB (K + V frags)
  if (ws_size >= need) {
    _Float16* kf = (_Float16*)d_ws;
    _Float16* vf = kf + NE;
    make_frags<<<1024, 256, 0, stream>>>(k, v, kf, vf);
    attn_fused<<<512, 512, 0, stream>>>(q, kf, vf, out);
  } else {
    attn_fallback<<<16384, 256, 0, stream>>>(q, k, v, out);
  }
}